// Round 5
// baseline (2327.897 us; speedup 1.0000x reference)
//
#include <hip/hip_runtime.h>
#include <stdint.h>

#define DD 256
#define DINF 128

typedef __attribute__((ext_vector_type(8))) short short8;
typedef __attribute__((ext_vector_type(4))) float f32x4;

__device__ __forceinline__ short f2bf(float f) {
    union { float f; uint32_t u; } c{f};
    uint32_t r = (c.u + 0x7fffu + ((c.u >> 16) & 1u)) >> 16;
    return (short)(uint16_t)r;
}

__device__ __forceinline__ float bf2f(uint16_t b) {
    union { uint32_t u; float f; } c;
    c.u = ((uint32_t)b) << 16;
    return c.f;
}

// ---------------- CSR build ----------------
__global__ void k_hist(const int* __restrict__ rows, int* __restrict__ counts, int E) {
    int e = blockIdx.x * blockDim.x + threadIdx.x;
    if (e < E) atomicAdd(&counts[rows[e] + 1], 1);
}

__global__ void k_scan1(const int* __restrict__ counts, int* __restrict__ part,
                        int* __restrict__ blksum, int n1) {
    __shared__ int tmp[1024];
    int b = blockIdx.x, t = threadIdx.x, i = b * 1024 + t;
    int v = (i < n1) ? counts[i] : 0;
    tmp[t] = v;
    __syncthreads();
    for (int off = 1; off < 1024; off <<= 1) {
        int a = (t >= off) ? tmp[t - off] : 0;
        __syncthreads();
        tmp[t] += a;
        __syncthreads();
    }
    if (i < n1) part[i] = tmp[t];
    if (t == 1023) blksum[b] = tmp[t];
}

__global__ void k_scan2(int* __restrict__ blksum, int nb) {
    __shared__ int tmp[1024];
    int t = threadIdx.x;
    int v = (t < nb) ? blksum[t] : 0;
    tmp[t] = v;
    __syncthreads();
    for (int off = 1; off < 1024; off <<= 1) {
        int a = (t >= off) ? tmp[t - off] : 0;
        __syncthreads();
        tmp[t] += a;
        __syncthreads();
    }
    if (t < nb) blksum[t] = tmp[t];
}

__global__ void k_scan3(const int* __restrict__ blksum, int* __restrict__ row_ptr,
                        int* __restrict__ cursor, int n1) {
    int i = blockIdx.x * blockDim.x + threadIdx.x;
    if (i < n1) {
        int b = i >> 10;
        int off = (b > 0) ? blksum[b - 1] : 0;
        int v = cursor[i] + off;
        row_ptr[i] = v;
        cursor[i] = v;
    }
}

__global__ void k_scatter(const int* __restrict__ rows, const int* __restrict__ cols,
                          const float* __restrict__ vals, int* __restrict__ cursor,
                          int* __restrict__ cols_s, float* __restrict__ vals_s, int E) {
    int e = blockIdx.x * blockDim.x + threadIdx.x;
    if (e < E) {
        int r = rows[e];
        int pos = atomicAdd(&cursor[r], 1);
        cols_s[pos] = cols[e];
        vals_s[pos] = vals[e];
    }
}

// ---------------- M = (W*clip(d))@W^T - I, packed in MFMA B-fragment order ----------------
__global__ void k_build_m(const float* __restrict__ W, const float* __restrict__ dvec,
                          uint16_t* __restrict__ Mpk) {
    __shared__ float u[DD];
    int n = blockIdx.x, k = threadIdx.x;
    float dj = dvec[k];
    dj = fminf(fmaxf(dj, 0.f), 1.f);
    u[k] = W[n * DD + k] * dj;
    __syncthreads();
    float acc = 0.f;
    for (int j = 0; j < DD; j++) acc += u[j] * W[k * DD + j];
    acc -= (n == k) ? 1.f : 0.f;
    int tile = n >> 4, m = n & 15, kt = k >> 5, quad = (k >> 3) & 3, j = k & 7;
    int lane = quad * 16 + m;
    Mpk[(((tile * 8 + kt) * 64 + lane) << 3) + j] = (uint16_t)f2bf(acc);
}

// ---------------- init: zn = [x,0] fp32, zp0 = bf16(zn), alpha = alpha0 ----------------
__global__ void k_init(const float* __restrict__ x, const float* __restrict__ alpha0,
                       float* __restrict__ zn, uint16_t* __restrict__ zp0,
                       float* __restrict__ alpha, int N) {
    int idx = blockIdx.x * blockDim.x + threadIdx.x;
    int total = N * 64;
    if (idx < total) {
        int row = idx >> 6, c4 = idx & 63;
        float4 v;
        if (c4 < 32) v = ((const float4*)x)[(size_t)row * 32 + c4];
        else v = make_float4(0.f, 0.f, 0.f, 0.f);
        ((float4*)zn)[idx] = v;
        ushort4 b;
        b.x = (uint16_t)f2bf(v.x); b.y = (uint16_t)f2bf(v.y);
        b.z = (uint16_t)f2bf(v.z); b.w = (uint16_t)f2bf(v.w);
        ((ushort4*)zp0)[idx] = b;
    }
    if (idx < N) alpha[idx] = alpha0[idx];
}

// ---------------- fused eval: SpMM gather + alpha + z@M (MFMA) + combine + RK4 --------
// Eval point z = zsrc (bf16). f = alph*(az - z) + z@M + x0
// All cross-row reads hit zsrc only; all writes go to OTHER buffers (ping-pong safe).
// mode 0: zeb_w = bf16(zn + c1*f) ; S = zn + c2*f        (eval1)
// mode 1: zeb_w = bf16(zn + c1*f) ; S += c2*f            (eval2,3)
// mode 2: zn_w = S + c2*f ; zeb_w = bf16(zn_w)           (eval4)
__global__ __launch_bounds__(256, 4) void k_eval(
    const uint16_t* __restrict__ zsrc, const float* __restrict__ zn,
    uint16_t* __restrict__ zeb_w, float* __restrict__ S, float* __restrict__ zn_w,
    const int* __restrict__ row_ptr, const int* __restrict__ cols_s,
    const float* __restrict__ vals_s,
    const uint16_t* __restrict__ Mpk, const float* __restrict__ x,
    const float* __restrict__ W_ih, const float* __restrict__ W_hh,
    const float* __restrict__ b_ih, const float* __restrict__ b_hh,
    const float* __restrict__ h, float* __restrict__ alpha,
    int N, int mode, float c1, float c2)
{
    __shared__ uint16_t zs[32][264];   // eval-point rows, bf16     16.9 KB
    __shared__ uint16_t ts[32][264];   // az, then t=g+a*(az-z)     16.9 KB
    __shared__ float wihs[2][DD];      //                            2.0 KB
    __shared__ float alph_s[32];
    // ~35.9 KB -> 4 blocks/CU

    int t = threadIdx.x;
    int r0 = blockIdx.x * 32;
    int wv = t >> 6;
    int lane = t & 63;

    // P0: stage own 32 bf16 rows from zsrc
    #pragma unroll
    for (int i = 0; i < 8; i++) {
        int idx = t + i * 256;
        int row = idx >> 6, c4 = idx & 63;
        int grow = r0 + row;
        ushort4 v = make_ushort4(0, 0, 0, 0);
        if (grow < N) v = ((const ushort4*)zsrc)[(size_t)grow * 64 + c4];
        *(ushort4*)&zs[row][c4 * 4] = v;
    }
    wihs[0][t] = W_ih[t];
    wihs[1][t] = W_ih[DD + t];

    // P1: SpMM gather — wave wv computes az for rows r0+wv*8 .. +7 -> ts (bf16)
    {
        int gr = r0 + wv * 8;
        for (int rr = 0; rr < 8; rr++) {
            int grow = gr + rr;
            float4 acc = make_float4(0.f, 0.f, 0.f, 0.f);
            if (grow < N) {
                int s = row_ptr[grow], e = row_ptr[grow + 1];
                int c_next = 0; float v_next = 0.f;
                if (s < e) { c_next = cols_s[s]; v_next = vals_s[s]; }
                for (int i = s; i < e; i++) {
                    int c = c_next; float v = v_next;
                    if (i + 1 < e) { c_next = cols_s[i + 1]; v_next = vals_s[i + 1]; }
                    ushort4 zr = ((const ushort4*)zsrc)[(size_t)c * 64 + lane];
                    acc.x += v * bf2f(zr.x); acc.y += v * bf2f(zr.y);
                    acc.z += v * bf2f(zr.z); acc.w += v * bf2f(zr.w);
                }
            }
            ushort4 o;
            o.x = (uint16_t)f2bf(acc.x); o.y = (uint16_t)f2bf(acc.y);
            o.z = (uint16_t)f2bf(acc.z); o.w = (uint16_t)f2bf(acc.w);
            *(ushort4*)&ts[wv * 8 + rr][lane * 4] = o;
        }
    }
    __syncthreads();

    // P2: RNNCell dots -> alpha update -> 0.5*sigmoid(alpha)
    {
        int row = t >> 3, part = t & 7;
        int cbeg = part * 32;
        float s0 = 0.f, s1 = 0.f;
        #pragma unroll 8
        for (int c = cbeg; c < cbeg + 32; c++) {
            float zv = bf2f(zs[row][c]);
            s0 += zv * wihs[0][c];
            s1 += zv * wihs[1][c];
        }
        s0 += __shfl_down(s0, 4, 8); s0 += __shfl_down(s0, 2, 8); s0 += __shfl_down(s0, 1, 8);
        s1 += __shfl_down(s1, 4, 8); s1 += __shfl_down(s1, 2, 8); s1 += __shfl_down(s1, 1, 8);
        if (part == 0) {
            int grow = r0 + row;
            if (grow < N) {
                float h0 = h[grow * 2], h1 = h[grow * 2 + 1];
                float cc0 = b_ih[0] + b_hh[0] + h0 * W_hh[0] + h1 * W_hh[1];
                float cc1 = b_ih[1] + b_hh[1] + h0 * W_hh[2] + h1 * W_hh[3];
                float a0 = tanhf(s0 + cc0);
                float a1 = tanhf(s1 + cc1);
                float al = alpha[grow];
                float anew = al * a0 + a1;
                alpha[grow] = anew;
                alph_s[row] = 0.5f / (1.f + expf(-anew));
            } else {
                alph_s[row] = 0.f;
            }
        }
    }

    // P2b: A fragments from LDS
    int m = lane & 15, quad = lane >> 4;
    int arow = (wv & 1) * 16 + m;
    int whichW = wv >> 1;
    short8 afr[8];
    #pragma unroll
    for (int kt = 0; kt < 8; kt++)
        afr[kt] = *(const short8*)&zs[arow][kt * 32 + quad * 8];
    __syncthreads();   // alph_s + ts ready for all waves

    // P3: MFMA over 8 column tiles; epilogue folds alpha*(az-z) into ts
    int lrb = (wv & 1) * 16 + quad * 4;
    #pragma unroll
    for (int nt = 0; nt < 8; nt++) {
        int tile = whichW * 8 + nt;
        f32x4 acc = {0.f, 0.f, 0.f, 0.f};
        #pragma unroll
        for (int kt = 0; kt < 8; kt++) {
            short8 b = ((const short8*)Mpk)[(tile * 8 + kt) * 64 + lane];
            acc = __builtin_amdgcn_mfma_f32_16x16x32_bf16(afr[kt], b, acc, 0, 0, 0);
        }
        int gcol = tile * 16 + m;
        #pragma unroll
        for (int r = 0; r < 4; r++) {
            int lr = lrb + r;
            float azv = bf2f(ts[lr][gcol]);
            float zv = bf2f(zs[lr][gcol]);
            float tv = acc[r] + alph_s[lr] * (azv - zv);
            ts[lr][gcol] = (uint16_t)f2bf(tv);
        }
    }
    __syncthreads();

    // P4: coalesced combine + RK4 (float4/ushort4 streams only)
    #pragma unroll
    for (int i = 0; i < 8; i++) {
        int idx = t + i * 256;
        int row = idx >> 6, c4 = idx & 63;
        int grow = r0 + row;
        if (grow >= N) continue;
        size_t b4 = (size_t)grow * 64 + c4;
        ushort4 t4 = *(const ushort4*)&ts[row][c4 * 4];
        float4 x4 = make_float4(0.f, 0.f, 0.f, 0.f);
        if (c4 < 32) x4 = ((const float4*)x)[(size_t)grow * 32 + c4];
        float f0 = bf2f(t4.x) + x4.x;
        float f1 = bf2f(t4.y) + x4.y;
        float f2 = bf2f(t4.z) + x4.z;
        float f3 = bf2f(t4.w) + x4.w;
        if (mode == 0) {
            float4 zb = ((const float4*)zn)[b4];
            ushort4 o;
            o.x = (uint16_t)f2bf(zb.x + c1 * f0); o.y = (uint16_t)f2bf(zb.y + c1 * f1);
            o.z = (uint16_t)f2bf(zb.z + c1 * f2); o.w = (uint16_t)f2bf(zb.w + c1 * f3);
            ((ushort4*)zeb_w)[b4] = o;
            float4 s4;
            s4.x = zb.x + c2 * f0; s4.y = zb.y + c2 * f1;
            s4.z = zb.z + c2 * f2; s4.w = zb.w + c2 * f3;
            ((float4*)S)[b4] = s4;
        } else if (mode == 1) {
            float4 zb = ((const float4*)zn)[b4];
            ushort4 o;
            o.x = (uint16_t)f2bf(zb.x + c1 * f0); o.y = (uint16_t)f2bf(zb.y + c1 * f1);
            o.z = (uint16_t)f2bf(zb.z + c1 * f2); o.w = (uint16_t)f2bf(zb.w + c1 * f3);
            ((ushort4*)zeb_w)[b4] = o;
            float4 s4 = ((const float4*)S)[b4];
            s4.x += c2 * f0; s4.y += c2 * f1; s4.z += c2 * f2; s4.w += c2 * f3;
            ((float4*)S)[b4] = s4;
        } else {
            float4 s4 = ((const float4*)S)[b4];
            float4 zr;
            zr.x = s4.x + c2 * f0; zr.y = s4.y + c2 * f1;
            zr.z = s4.z + c2 * f2; zr.w = s4.w + c2 * f3;
            ((float4*)zn_w)[b4] = zr;
            ushort4 o;
            o.x = (uint16_t)f2bf(zr.x); o.y = (uint16_t)f2bf(zr.y);
            o.z = (uint16_t)f2bf(zr.z); o.w = (uint16_t)f2bf(zr.w);
            ((ushort4*)zeb_w)[b4] = o;
        }
    }
}

// ---------------- output: first 128 cols of zn ----------------
__global__ void k_out(const float* __restrict__ zn, float* __restrict__ out, int N) {
    int idx = blockIdx.x * blockDim.x + threadIdx.x;
    if (idx < N * 32) {
        int row = idx >> 5, c4 = idx & 31;
        ((float4*)out)[idx] = ((const float4*)zn)[(size_t)row * 64 + c4];
    }
}

__global__ void k_fill(float* __restrict__ out, int n, float v) {
    int idx = blockIdx.x * blockDim.x + threadIdx.x;
    if (idx < n) out[idx] = v;
}

static inline size_t alignup(size_t v) { return (v + 255) & ~(size_t)255; }

extern "C" void kernel_launch(void* const* d_in, const int* in_sizes, int n_in,
                              void* d_out, int out_size, void* d_ws, size_t ws_size,
                              hipStream_t stream) {
    const float* x      = (const float*)d_in[0];
    const int*   erow   = (const int*)d_in[1];
    const int*   ecol   = (const int*)d_in[2];
    const float* evals  = (const float*)d_in[3];
    const float* W_ih   = (const float*)d_in[4];
    const float* W_hh   = (const float*)d_in[5];
    const float* b_ih   = (const float*)d_in[6];
    const float* b_hh   = (const float*)d_in[7];
    const float* h      = (const float*)d_in[8];
    const float* alpha0 = (const float*)d_in[9];
    const float* W      = (const float*)d_in[10];
    const float* dvec   = (const float*)d_in[11];

    int N = in_sizes[0] / DINF;
    int E = in_sizes[1];

    char* w = (char*)d_ws;
    float* zn = (float*)w;        w += alignup((size_t)N * DD * 4);   // 102.4 MB
    float* S  = (float*)w;        w += alignup((size_t)N * DD * 4);   // 102.4 MB
    uint16_t* zp0 = (uint16_t*)w; w += alignup((size_t)N * DD * 2);   //  51.2 MB
    float* alpha = (float*)w;     w += alignup((size_t)N * 4);
    uint16_t* Mpk = (uint16_t*)w; w += alignup((size_t)DD * DD * 2);
    int* counts = (int*)w;        w += alignup((size_t)(N + 1) * 4);
    int* row_ptr = (int*)w;       w += alignup((size_t)(N + 1) * 4);
    int* cursor = (int*)w;        w += alignup((size_t)(N + 1) * 4);
    int* blksum = (int*)w;        w += alignup((size_t)1024 * 4);
    int* cols_s = (int*)w;        w += alignup((size_t)E * 4);
    float* vals_s = (float*)w;    w += alignup((size_t)E * 4);
    size_t need = (size_t)(w - (char*)d_ws);   // ~264 MB

    // zp1 (bf16 ping-pong partner, 51.2 MB) lives in d_out; dead before final k_out.
    uint16_t* zp1 = (uint16_t*)d_out;

    if (ws_size < need) {
        k_fill<<<(out_size + 255) / 256, 256, 0, stream>>>((float*)d_out, out_size, 1000.0f);
        return;
    }

    int n1 = N + 1, nb = (n1 + 1023) / 1024;
    hipMemsetAsync(counts, 0, (size_t)n1 * 4, stream);
    k_hist<<<(E + 255) / 256, 256, 0, stream>>>(erow, counts, E);
    k_scan1<<<nb, 1024, 0, stream>>>(counts, cursor, blksum, n1);
    k_scan2<<<1, 1024, 0, stream>>>(blksum, nb);
    k_scan3<<<(n1 + 255) / 256, 256, 0, stream>>>(blksum, row_ptr, cursor, n1);
    k_scatter<<<(E + 255) / 256, 256, 0, stream>>>(erow, ecol, evals, cursor, cols_s, vals_s, E);

    k_build_m<<<DD, DD, 0, stream>>>(W, dvec, Mpk);
    k_init<<<(N * 64 + 255) / 256, 256, 0, stream>>>(x, alpha0, zn, zp0, alpha, N);

    const float dt = 0.45f;  // T_END / N_STEPS
    int ge = (N + 31) / 32;
    for (int s = 0; s < 2; s++) {
        // eval1: z=zn (zp0 holds bf16(zn)); out eval-point -> zp1
        k_eval<<<ge, 256, 0, stream>>>(zp0, zn, zp1, S, nullptr, row_ptr, cols_s, vals_s,
                                       Mpk, x, W_ih, W_hh, b_ih, b_hh, h, alpha,
                                       N, 0, 0.5f * dt, dt / 6.f);
        // eval2: z=zp1 -> zp0
        k_eval<<<ge, 256, 0, stream>>>(zp1, zn, zp0, S, nullptr, row_ptr, cols_s, vals_s,
                                       Mpk, x, W_ih, W_hh, b_ih, b_hh, h, alpha,
                                       N, 1, 0.5f * dt, dt / 3.f);
        // eval3: z=zp0 -> zp1
        k_eval<<<ge, 256, 0, stream>>>(zp0, zn, zp1, S, nullptr, row_ptr, cols_s, vals_s,
                                       Mpk, x, W_ih, W_hh, b_ih, b_hh, h, alpha,
                                       N, 1, dt, dt / 3.f);
        // eval4: z=zp1 -> new zn (fp32) + zp0 = bf16(zn_next)
        k_eval<<<ge, 256, 0, stream>>>(zp1, zn, zp0, S, zn, row_ptr, cols_s, vals_s,
                                       Mpk, x, W_ih, W_hh, b_ih, b_hh, h, alpha,
                                       N, 2, 0.f, dt / 6.f);
    }

    k_out<<<(N * 32 + 255) / 256, 256, 0, stream>>>(zn, (float*)d_out, N);
}

// Round 6
// 1963.538 us; speedup vs baseline: 1.1856x; 1.1856x over previous
//
#include <hip/hip_runtime.h>
#include <stdint.h>

#define DD 256
#define DINF 128

typedef __attribute__((ext_vector_type(8))) short short8;
typedef __attribute__((ext_vector_type(4))) float f32x4;

__device__ __forceinline__ short f2bf(float f) {
    union { float f; uint32_t u; } c{f};
    uint32_t r = (c.u + 0x7fffu + ((c.u >> 16) & 1u)) >> 16;
    return (short)(uint16_t)r;
}

__device__ __forceinline__ float bf2f(uint16_t b) {
    union { uint32_t u; float f; } c;
    c.u = ((uint32_t)b) << 16;
    return c.f;
}

// ---------------- CSR build ----------------
__global__ void k_hist(const int* __restrict__ rows, int* __restrict__ counts, int E) {
    int e = blockIdx.x * blockDim.x + threadIdx.x;
    if (e < E) atomicAdd(&counts[rows[e] + 1], 1);
}

__global__ void k_scan1(const int* __restrict__ counts, int* __restrict__ part,
                        int* __restrict__ blksum, int n1) {
    __shared__ int tmp[1024];
    int b = blockIdx.x, t = threadIdx.x, i = b * 1024 + t;
    int v = (i < n1) ? counts[i] : 0;
    tmp[t] = v;
    __syncthreads();
    for (int off = 1; off < 1024; off <<= 1) {
        int a = (t >= off) ? tmp[t - off] : 0;
        __syncthreads();
        tmp[t] += a;
        __syncthreads();
    }
    if (i < n1) part[i] = tmp[t];
    if (t == 1023) blksum[b] = tmp[t];
}

__global__ void k_scan2(int* __restrict__ blksum, int nb) {
    __shared__ int tmp[1024];
    int t = threadIdx.x;
    int v = (t < nb) ? blksum[t] : 0;
    tmp[t] = v;
    __syncthreads();
    for (int off = 1; off < 1024; off <<= 1) {
        int a = (t >= off) ? tmp[t - off] : 0;
        __syncthreads();
        tmp[t] += a;
        __syncthreads();
    }
    if (t < nb) blksum[t] = tmp[t];
}

// finalizes row_ptr in place (it holds block-local scans) and mirrors into cursor
__global__ void k_scan3(const int* __restrict__ blksum, int* __restrict__ row_ptr,
                        int* __restrict__ cursor, int n1) {
    int i = blockIdx.x * blockDim.x + threadIdx.x;
    if (i < n1) {
        int b = i >> 10;
        int off = (b > 0) ? blksum[b - 1] : 0;
        int v = row_ptr[i] + off;
        row_ptr[i] = v;
        cursor[i] = v;
    }
}

__global__ void k_scatter(const int* __restrict__ rows, const int* __restrict__ cols,
                          const float* __restrict__ vals, int* __restrict__ cursor,
                          int* __restrict__ cols_s, float* __restrict__ vals_s, int E) {
    int e = blockIdx.x * blockDim.x + threadIdx.x;
    if (e < E) {
        int r = rows[e];
        int pos = atomicAdd(&cursor[r], 1);
        cols_s[pos] = cols[e];
        vals_s[pos] = vals[e];
    }
}

// ---------------- M = (W*clip(d))@W^T - I, packed in MFMA B-fragment order ----------------
__global__ void k_build_m(const float* __restrict__ W, const float* __restrict__ dvec,
                          uint16_t* __restrict__ Mpk) {
    __shared__ float u[DD];
    int n = blockIdx.x, k = threadIdx.x;
    float dj = dvec[k];
    dj = fminf(fmaxf(dj, 0.f), 1.f);
    u[k] = W[n * DD + k] * dj;
    __syncthreads();
    float acc = 0.f;
    for (int j = 0; j < DD; j++) acc += u[j] * W[k * DD + j];
    acc -= (n == k) ? 1.f : 0.f;
    int tile = n >> 4, m = n & 15, kt = k >> 5, quad = (k >> 3) & 3, j = k & 7;
    int lane = quad * 16 + m;
    Mpk[(((tile * 8 + kt) * 64 + lane) << 3) + j] = (uint16_t)f2bf(acc);
}

// ---------------- init: znb = bf16([x,0]), alpha = alpha0 ----------------
__global__ void k_init(const float* __restrict__ x, const float* __restrict__ alpha0,
                       uint16_t* __restrict__ znb, float* __restrict__ alpha, int N) {
    int idx = blockIdx.x * blockDim.x + threadIdx.x;
    int total = N * 64;
    if (idx < total) {
        int row = idx >> 6, c4 = idx & 63;
        float4 v = make_float4(0.f, 0.f, 0.f, 0.f);
        if (c4 < 32) v = ((const float4*)x)[(size_t)row * 32 + c4];
        ushort4 b;
        b.x = (uint16_t)f2bf(v.x); b.y = (uint16_t)f2bf(v.y);
        b.z = (uint16_t)f2bf(v.z); b.w = (uint16_t)f2bf(v.w);
        ((ushort4*)znb)[idx] = b;
    }
    if (idx < N) alpha[idx] = alpha0[idx];
}

// ---------------- SpMM + alpha: az = bf16(A*z); alpha update; alph = 0.5*sigmoid ------
__global__ void k_spmm(const uint16_t* __restrict__ z, const int* __restrict__ row_ptr,
                       const int* __restrict__ cols_s, const float* __restrict__ vals_s,
                       const float* __restrict__ W_ih, const float* __restrict__ W_hh,
                       const float* __restrict__ b_ih, const float* __restrict__ b_hh,
                       const float* __restrict__ hbuf, float* __restrict__ alpha,
                       float* __restrict__ alph, uint16_t* __restrict__ az, int N) {
    int wave = (int)((blockIdx.x * (size_t)blockDim.x + threadIdx.x) >> 6);
    int lane = threadIdx.x & 63;
    if (wave >= N) return;

    // own-row eval point (cols 4*lane..+3)
    ushort4 zr4 = ((const ushort4*)z)[(size_t)wave * 64 + lane];
    float z0 = bf2f(zr4.x), z1 = bf2f(zr4.y), z2 = bf2f(zr4.z), z3 = bf2f(zr4.w);

    // RNNCell dot partials
    float4 w0 = ((const float4*)W_ih)[lane];
    float4 w1 = ((const float4*)(W_ih + DD))[lane];
    float s0 = z0 * w0.x + z1 * w0.y + z2 * w0.z + z3 * w0.w;
    float s1 = z0 * w1.x + z1 * w1.y + z2 * w1.z + z3 * w1.w;

    // gather
    int s = row_ptr[wave], e = row_ptr[wave + 1];
    float4 acc = make_float4(0.f, 0.f, 0.f, 0.f);
    int c_next = 0; float v_next = 0.f;
    if (s < e) { c_next = cols_s[s]; v_next = vals_s[s]; }
    for (int i = s; i < e; i++) {
        int c = c_next; float v = v_next;
        if (i + 1 < e) { c_next = cols_s[i + 1]; v_next = vals_s[i + 1]; }
        ushort4 zr = ((const ushort4*)z)[(size_t)c * 64 + lane];
        acc.x += v * bf2f(zr.x); acc.y += v * bf2f(zr.y);
        acc.z += v * bf2f(zr.z); acc.w += v * bf2f(zr.w);
    }
    ushort4 o;
    o.x = (uint16_t)f2bf(acc.x); o.y = (uint16_t)f2bf(acc.y);
    o.z = (uint16_t)f2bf(acc.z); o.w = (uint16_t)f2bf(acc.w);
    ((ushort4*)az)[(size_t)wave * 64 + lane] = o;

    // wave-reduce the dots, lane 0 does the alpha update
    #pragma unroll
    for (int off = 32; off >= 1; off >>= 1) {
        s0 += __shfl_down(s0, off, 64);
        s1 += __shfl_down(s1, off, 64);
    }
    if (lane == 0) {
        float h0 = hbuf[wave * 2], h1 = hbuf[wave * 2 + 1];
        float cc0 = b_ih[0] + b_hh[0] + h0 * W_hh[0] + h1 * W_hh[1];
        float cc1 = b_ih[1] + b_hh[1] + h0 * W_hh[2] + h1 * W_hh[3];
        float anew = alpha[wave] * tanhf(s0 + cc0) + tanhf(s1 + cc1);
        alpha[wave] = anew;
        alph[wave] = 0.5f / (1.f + expf(-anew));
    }
}

// ---------------- eval: z@M (MFMA) + combine + RK4 ----------------
// f = alph*(az - z) + z@M + x0   (z = zsrc rows, staged in LDS)
// mode 0: zout = bf16(z + c1*f) ; S = z + c2*f         (eval1: base == zsrc)
// mode 1: zout = bf16(znb + c1*f) ; S += c2*f          (eval2,3)
// mode 2: zout(=znb) = bf16(S + c2*f)                  (eval4)
__global__ __launch_bounds__(256, 4) void k_eval(
    const uint16_t* __restrict__ zsrc, const uint16_t* __restrict__ znb,
    uint16_t* __restrict__ zout, float* __restrict__ S,
    const uint16_t* __restrict__ az, const uint16_t* __restrict__ Mpk,
    const float* __restrict__ x, const float* __restrict__ alph,
    int N, int mode, float c1, float c2)
{
    __shared__ uint16_t zs[32][264];   // eval-point rows, bf16   16.9 KB
    __shared__ uint16_t gs[32][264];   // z@M result, bf16        16.9 KB
    __shared__ float alph_s[32];
    // ~34 KB -> 4 blocks/CU

    int t = threadIdx.x;
    int r0 = blockIdx.x * 32;
    int wv = t >> 6;
    int lane = t & 63;

    // P0: stage own 32 bf16 rows + alph
    #pragma unroll
    for (int i = 0; i < 8; i++) {
        int idx = t + i * 256;
        int row = idx >> 6, c4 = idx & 63;
        int grow = r0 + row;
        ushort4 v = make_ushort4(0, 0, 0, 0);
        if (grow < N) v = ((const ushort4*)zsrc)[(size_t)grow * 64 + c4];
        *(ushort4*)&zs[row][c4 * 4] = v;
    }
    if (t < 32) {
        int grow = r0 + t;
        alph_s[t] = (grow < N) ? alph[grow] : 0.f;
    }
    __syncthreads();

    // P1: A fragments from LDS
    int m = lane & 15, quad = lane >> 4;
    int arow = (wv & 1) * 16 + m;
    int whichW = wv >> 1;
    short8 afr[8];
    #pragma unroll
    for (int kt = 0; kt < 8; kt++)
        afr[kt] = *(const short8*)&zs[arow][kt * 32 + quad * 8];

    // P2: MFMA over 8 column tiles; B fragments from global (L2-resident Mpk)
    int lrb = (wv & 1) * 16 + quad * 4;
    #pragma unroll
    for (int nt = 0; nt < 8; nt++) {
        int tile = whichW * 8 + nt;
        f32x4 acc = {0.f, 0.f, 0.f, 0.f};
        #pragma unroll
        for (int kt = 0; kt < 8; kt++) {
            short8 b = ((const short8*)Mpk)[(tile * 8 + kt) * 64 + lane];
            acc = __builtin_amdgcn_mfma_f32_16x16x32_bf16(afr[kt], b, acc, 0, 0, 0);
        }
        int gcol = tile * 16 + m;
        #pragma unroll
        for (int r = 0; r < 4; r++)
            gs[lrb + r][gcol] = (uint16_t)f2bf(acc[r]);
    }
    __syncthreads();

    // P3: coalesced combine + RK4 (pure float4/ushort4 streams)
    #pragma unroll
    for (int i = 0; i < 8; i++) {
        int idx = t + i * 256;
        int row = idx >> 6, c4 = idx & 63;
        int grow = r0 + row;
        if (grow >= N) continue;
        size_t b4 = (size_t)grow * 64 + c4;
        float al = alph_s[row];
        ushort4 a4 = ((const ushort4*)az)[b4];
        ushort4 z4 = *(const ushort4*)&zs[row][c4 * 4];
        ushort4 g4 = *(const ushort4*)&gs[row][c4 * 4];
        float4 x4 = make_float4(0.f, 0.f, 0.f, 0.f);
        if (c4 < 32) x4 = ((const float4*)x)[(size_t)grow * 32 + c4];
        float zv0 = bf2f(z4.x), zv1 = bf2f(z4.y), zv2 = bf2f(z4.z), zv3 = bf2f(z4.w);
        float f0 = al * (bf2f(a4.x) - zv0) + bf2f(g4.x) + x4.x;
        float f1 = al * (bf2f(a4.y) - zv1) + bf2f(g4.y) + x4.y;
        float f2 = al * (bf2f(a4.z) - zv2) + bf2f(g4.z) + x4.z;
        float f3 = al * (bf2f(a4.w) - zv3) + bf2f(g4.w) + x4.w;
        if (mode == 0) {
            ushort4 o;
            o.x = (uint16_t)f2bf(zv0 + c1 * f0); o.y = (uint16_t)f2bf(zv1 + c1 * f1);
            o.z = (uint16_t)f2bf(zv2 + c1 * f2); o.w = (uint16_t)f2bf(zv3 + c1 * f3);
            ((ushort4*)zout)[b4] = o;
            float4 s4;
            s4.x = zv0 + c2 * f0; s4.y = zv1 + c2 * f1;
            s4.z = zv2 + c2 * f2; s4.w = zv3 + c2 * f3;
            ((float4*)S)[b4] = s4;
        } else if (mode == 1) {
            ushort4 zb = ((const ushort4*)znb)[b4];
            ushort4 o;
            o.x = (uint16_t)f2bf(bf2f(zb.x) + c1 * f0);
            o.y = (uint16_t)f2bf(bf2f(zb.y) + c1 * f1);
            o.z = (uint16_t)f2bf(bf2f(zb.z) + c1 * f2);
            o.w = (uint16_t)f2bf(bf2f(zb.w) + c1 * f3);
            ((ushort4*)zout)[b4] = o;
            float4 s4 = ((const float4*)S)[b4];
            s4.x += c2 * f0; s4.y += c2 * f1; s4.z += c2 * f2; s4.w += c2 * f3;
            ((float4*)S)[b4] = s4;
        } else {
            float4 s4 = ((const float4*)S)[b4];
            ushort4 o;
            o.x = (uint16_t)f2bf(s4.x + c2 * f0); o.y = (uint16_t)f2bf(s4.y + c2 * f1);
            o.z = (uint16_t)f2bf(s4.z + c2 * f2); o.w = (uint16_t)f2bf(s4.w + c2 * f3);
            ((ushort4*)zout)[b4] = o;
        }
    }
}

// ---------------- output: first 128 cols of znb -> fp32 ----------------
__global__ void k_out(const uint16_t* __restrict__ znb, float* __restrict__ out, int N) {
    int idx = blockIdx.x * blockDim.x + threadIdx.x;
    if (idx < N * 32) {
        int row = idx >> 5, c4 = idx & 31;
        ushort4 v = ((const ushort4*)znb)[(size_t)row * 64 + c4];
        float4 o;
        o.x = bf2f(v.x); o.y = bf2f(v.y); o.z = bf2f(v.z); o.w = bf2f(v.w);
        ((float4*)out)[idx] = o;
    }
}

__global__ void k_fill(float* __restrict__ out, int n, float v) {
    int idx = blockIdx.x * blockDim.x + threadIdx.x;
    if (idx < n) out[idx] = v;
}

static inline size_t alignup(size_t v) { return (v + 255) & ~(size_t)255; }

extern "C" void kernel_launch(void* const* d_in, const int* in_sizes, int n_in,
                              void* d_out, int out_size, void* d_ws, size_t ws_size,
                              hipStream_t stream) {
    const float* x      = (const float*)d_in[0];
    const int*   erow   = (const int*)d_in[1];
    const int*   ecol   = (const int*)d_in[2];
    const float* evals  = (const float*)d_in[3];
    const float* W_ih   = (const float*)d_in[4];
    const float* W_hh   = (const float*)d_in[5];
    const float* b_ih   = (const float*)d_in[6];
    const float* b_hh   = (const float*)d_in[7];
    const float* h      = (const float*)d_in[8];
    const float* alpha0 = (const float*)d_in[9];
    const float* W      = (const float*)d_in[10];
    const float* dvec   = (const float*)d_in[11];

    int N = in_sizes[0] / DINF;
    int E = in_sizes[1];

    char* w = (char*)d_ws;
    uint16_t* znb = (uint16_t*)w; w += alignup((size_t)N * DD * 2);   //  51.2 MB
    float* S  = (float*)w;        w += alignup((size_t)N * DD * 4);   // 102.4 MB
    uint16_t* zpA = (uint16_t*)w; w += alignup((size_t)N * DD * 2);   //  51.2 MB
    uint16_t* az = (uint16_t*)w;  w += alignup((size_t)N * DD * 2);   //  51.2 MB
    float* alpha = (float*)w;     w += alignup((size_t)N * 4);
    float* alph = (float*)w;      w += alignup((size_t)N * 4);
    uint16_t* Mpk = (uint16_t*)w; w += alignup((size_t)DD * DD * 2);
    int* counts = (int*)w;        w += alignup((size_t)(N + 1) * 4);  // reused as cursor
    int* row_ptr = (int*)w;       w += alignup((size_t)(N + 1) * 4);
    int* blksum = (int*)w;        w += alignup((size_t)1024 * 4);
    int* cols_s = (int*)w;        w += alignup((size_t)E * 4);
    float* vals_s = (float*)w;    w += alignup((size_t)E * 4);
    size_t need = (size_t)(w - (char*)d_ws);   // ~264 MB (same as R4)

    // zpB (bf16 ping-pong partner, 51.2 MB) lives in d_out; dead before final k_out.
    uint16_t* zpB = (uint16_t*)d_out;

    if (ws_size < need) {
        k_fill<<<(out_size + 255) / 256, 256, 0, stream>>>((float*)d_out, out_size, 1000.0f);
        return;
    }

    int n1 = N + 1, nb = (n1 + 1023) / 1024;
    hipMemsetAsync(counts, 0, (size_t)n1 * 4, stream);
    k_hist<<<(E + 255) / 256, 256, 0, stream>>>(erow, counts, E);
    k_scan1<<<nb, 1024, 0, stream>>>(counts, row_ptr, blksum, n1);
    k_scan2<<<1, 1024, 0, stream>>>(blksum, nb);
    k_scan3<<<(n1 + 255) / 256, 256, 0, stream>>>(blksum, row_ptr, counts, n1);
    k_scatter<<<(E + 255) / 256, 256, 0, stream>>>(erow, ecol, evals, counts, cols_s, vals_s, E);

    k_build_m<<<DD, DD, 0, stream>>>(W, dvec, Mpk);
    k_init<<<(N * 64 + 255) / 256, 256, 0, stream>>>(x, alpha0, znb, alpha, N);

    const float dt = 0.45f;  // T_END / N_STEPS
    int gs = (N + 3) / 4, ge = (N + 31) / 32;
    for (int s = 0; s < 2; s++) {
        // eval1: z = znb -> eval point zpA
        k_spmm<<<gs, 256, 0, stream>>>(znb, row_ptr, cols_s, vals_s, W_ih, W_hh,
                                       b_ih, b_hh, h, alpha, alph, az, N);
        k_eval<<<ge, 256, 0, stream>>>(znb, znb, zpA, S, az, Mpk, x, alph,
                                       N, 0, 0.5f * dt, dt / 6.f);
        // eval2: z = zpA -> zpB
        k_spmm<<<gs, 256, 0, stream>>>(zpA, row_ptr, cols_s, vals_s, W_ih, W_hh,
                                       b_ih, b_hh, h, alpha, alph, az, N);
        k_eval<<<ge, 256, 0, stream>>>(zpA, znb, zpB, S, az, Mpk, x, alph,
                                       N, 1, 0.5f * dt, dt / 3.f);
        // eval3: z = zpB -> zpA
        k_spmm<<<gs, 256, 0, stream>>>(zpB, row_ptr, cols_s, vals_s, W_ih, W_hh,
                                       b_ih, b_hh, h, alpha, alph, az, N);
        k_eval<<<ge, 256, 0, stream>>>(zpB, znb, zpA, S, az, Mpk, x, alph,
                                       N, 1, dt, dt / 3.f);
        // eval4: z = zpA -> new state znb (also next step's eval1 source)
        k_spmm<<<gs, 256, 0, stream>>>(zpA, row_ptr, cols_s, vals_s, W_ih, W_hh,
                                       b_ih, b_hh, h, alpha, alph, az, N);
        k_eval<<<ge, 256, 0, stream>>>(zpA, znb, znb, S, az, Mpk, x, alph,
                                       N, 2, 0.f, dt / 6.f);
    }

    k_out<<<(N * 32 + 255) / 256, 256, 0, stream>>>(znb, (float*)d_out, N);
}